// Round 21
// baseline (133.798 us; speedup 1.0000x reference)
//
#include <hip/hip_runtime.h>
#include <hip/hip_bf16.h>

using bf8_t = __attribute__((ext_vector_type(8))) short;
using bf4_t = __attribute__((ext_vector_type(4))) short;
using u16x4 = __attribute__((ext_vector_type(4))) unsigned short;
using f32x4 = __attribute__((ext_vector_type(4))) float;

constexpr int B_   = 8;
constexpr int N_   = 300;
constexpr int L_   = 4096;
constexpr int C_   = 256;
constexpr int H_   = 8;
constexpr int NPAD = 320;          // 5 row-tiles of 64
constexpr int QT_  = 5;            // q tiles of 64
constexpr int SPL_ = 4;            // KV splits; B*H*SPL = 256 = 0 mod 8 (XCD-aligned)
constexpr int TPS_ = 16;           // 64-key tiles per split
// scale folded with log2(e) so softmax uses native exp2 (v_exp_f32)
constexpr float SCALE = 0.18033688011112042f;   // (2*32)^-0.5 * log2(e)

__device__ __forceinline__ unsigned short f2b(float f) {
  unsigned u = __float_as_uint(f);
  u += 0x7FFFu + ((u >> 16) & 1u);          // RNE
  return (unsigned short)(u >> 16);
}

// convert 16 contiguous f32 -> 16 bf16 into LDS (dst 16B-aligned)
__device__ __forceinline__ void stage_cvt16(unsigned short* dst, const float* src) {
#pragma unroll
  for (int half = 0; half < 2; ++half) {
    f32x4 x0 = *(const f32x4*)(src + half * 8);
    f32x4 x1 = *(const f32x4*)(src + half * 8 + 4);
    bf8_t v;
#pragma unroll
    for (int j = 0; j < 4; ++j) { v[j] = (short)f2b(x0[j]); v[4 + j] = (short)f2b(x1[j]); }
    *(bf8_t*)(dst + half * 8) = v;
  }
}

__device__ __forceinline__ void gload_lds16(const void* g, void* l) {
  __builtin_amdgcn_global_load_lds(
      (const __attribute__((address_space(1))) unsigned int*)g,
      (__attribute__((address_space(3))) unsigned int*)l, 16, 0, 0);
}

__device__ __forceinline__ unsigned cvt_pk_bf16(float lo, float hi) {
  unsigned r;
  asm("v_cvt_pk_bf16_f32 %0, %1, %2" : "=v"(r) : "v"(lo), "v"(hi));
  return r;
}

// ---------------- weight pre-convert (single launch, both layouts) --------------
// kv family (W0..W2 -> Wk): BK=32 tiles, slot i*8+x, XOR(d&3).
// q  family (W3..W5 -> Wq): BK=64 tiles, slot i*4+x (x<4 only), XOR(d&7).
__global__ __launch_bounds__(256) void wcvt_all_k(
    const float* __restrict__ W0, const float* __restrict__ W1, const float* __restrict__ W2,
    const float* __restrict__ W3, const float* __restrict__ W4, const float* __restrict__ W5,
    unsigned short* __restrict__ Wk, unsigned short* __restrict__ Wq)
{
  const float* Wkv[3] = {W0, W1, W2};
  const float* Wqq[3] = {W3, W4, W5};
  const int x = blockIdx.x, i = blockIdx.y;        // x in 0..7, i in 0..2
  const int d = threadIdx.x;
  {  // kv: 32-wide tile x
    const float* src = Wkv[i] + (size_t)d * C_ + x * 32;
    unsigned short* dst = Wk + ((size_t)(i * 8 + x) * 256 + d) * 32;
#pragma unroll
    for (int g = 0; g < 4; ++g) {
      f32x4 a = *(const f32x4*)(src + g * 8);
      f32x4 b = *(const f32x4*)(src + g * 8 + 4);
      bf8_t v;
#pragma unroll
      for (int j = 0; j < 4; ++j) { v[j] = (short)f2b(a[j]); v[4 + j] = (short)f2b(b[j]); }
      *(bf8_t*)(dst + (g ^ (d & 3)) * 8) = v;
    }
  }
  if (x < 4) {  // q: 64-wide tile x
    const float* src = Wqq[i] + (size_t)d * C_ + x * 64;
    unsigned short* dst = Wq + ((size_t)(i * 4 + x) * 256 + d) * 64;
#pragma unroll
    for (int g = 0; g < 8; ++g) {
      f32x4 a = *(const f32x4*)(src + g * 8);
      f32x4 b = *(const f32x4*)(src + g * 8 + 4);
      bf8_t v;
#pragma unroll
      for (int j = 0; j < 4; ++j) { v[j] = (short)f2b(a[j]); v[4 + j] = (short)f2b(b[j]); }
      *(bf8_t*)(dst + (g ^ (d & 7)) * 8) = v;
    }
  }
}

// ---------------- K-side projections: A-resident, streaming prologue ------------
// LDS 64 KB: A [64][256] bf16 resident (XOR slot g^(row&7)) + B dbuf 2x16 KB.
// Prologue streams the A tile contiguously (256 B/thread rows) once; main loop
// barriers drain only L2-hit B gloads. V written with sigma_G column permute.
__global__ __launch_bounds__(256, 2) void kvproj_k(
    const float* __restrict__ xp, const float* __restrict__ xk, const float* __restrict__ xv,
    const unsigned short* __restrict__ Wk,
    const float* __restrict__ bkp, const float* __restrict__ bkc, const float* __restrict__ bv,
    unsigned short* __restrict__ Kc, unsigned short* __restrict__ Kp, unsigned short* __restrict__ Vt)
{
  __shared__ __align__(16) unsigned short LB[32768];   // 64 KB: A@[0,16384), B@16384/24576
  const int tid = threadIdx.x, lane = tid & 63, wv = tid >> 6;
  const int fr = lane & 15, fg = lane >> 4;
  const int i = blockIdx.y;
  const int row0 = blockIdx.x * 64;
  const int b = row0 >> 12, ll0 = row0 & (L_ - 1);
  const float* X    = (i == 0) ? xp  : (i == 1) ? xk  : xv;
  const float* bias = (i == 0) ? bkp : (i == 1) ? bkc : bv;

  const int ar = tid >> 2, ac = tid & 3;               // A-stage: row, col-quarter

  f32x4 acc[4][4] = {};

  const unsigned short* Wi = Wk + (size_t)i * 8 * 8192;

  auto stageB = [&](int step, int buf) {
    const char* src = (const char*)(Wi + step * 8192);
    char* dst = (char*)(LB + 16384 + buf * 8192);
#pragma unroll
    for (int c = 0; c < 4; ++c) {
      const int off = c * 4096 + tid * 16;
      gload_lds16(src + off, dst + off);
    }
  };

  // prologue: B(0) + stream the full 64x256 A tile (contiguous 256 B per thread)
  stageB(0, 0);
  {
    const float* s = X + (size_t)(row0 + ar) * C_ + ac * 64;
    unsigned short* arow = LB + ar * 256;
#pragma unroll
    for (int j = 0; j < 8; ++j) {
      f32x4 a0 = *(const f32x4*)(s + j * 8);
      f32x4 a1 = *(const f32x4*)(s + j * 8 + 4);
      bf8_t v;
#pragma unroll
      for (int q = 0; q < 4; ++q) { v[q] = (short)f2b(a0[q]); v[4 + q] = (short)f2b(a1[q]); }
      const int g = ac * 8 + j;
      *(bf8_t*)(arow + ((g ^ (ar & 7)) * 8)) = v;
    }
  }
  __syncthreads();

  int cur = 0;
  const int gx = (fg ^ (fr & 3)) * 8;
  for (int step = 0; step < 8; ++step) {
    const int nxt = cur ^ 1;
    if (step < 7) stageB(step + 1, nxt);
    const unsigned short* Bb = LB + 16384 + cur * 8192;
    bf8_t xf[4];
#pragma unroll
    for (int mt = 0; mt < 4; ++mt) {
      const int row = mt * 16 + fr;
      const int slot = (step * 4 + fg) ^ (fr & 7);
      xf[mt] = *(const bf8_t*)(LB + row * 256 + slot * 8);
    }
#pragma unroll
    for (int nt = 0; nt < 4; ++nt) {
      bf8_t wf = *(const bf8_t*)(Bb + (wv * 64 + nt * 16 + fr) * 32 + gx);
#pragma unroll
      for (int mt = 0; mt < 4; ++mt)
        acc[nt][mt] = __builtin_amdgcn_mfma_f32_16x16x32_bf16(wf, xf[mt], acc[nt][mt], 0, 0, 0);
    }
    __syncthreads();
    cur = nxt;
  }

  if (i < 2) {
    unsigned short* outp = (i == 0) ? Kp : Kc;
#pragma unroll
    for (int nt = 0; nt < 4; ++nt) {
      const int d0 = wv * 64 + nt * 16 + fg * 4;
      const f32x4 bb = *(const f32x4*)(bias + d0);
      const int h = d0 >> 5, dh = d0 & 31;
#pragma unroll
      for (int mt = 0; mt < 4; ++mt) {
        const int l = ll0 + mt * 16 + fr;
        u16x4 v;
#pragma unroll
        for (int r = 0; r < 4; ++r) v[r] = f2b(acc[nt][mt][r] + bb[r]);
        *(u16x4*)(outp + ((size_t)(b * H_ + h) * L_ + l) * 32 + dh) = v;
      }
    }
  } else {
    // V: transpose through LDS (row stride 68 u16) -> Vt[b][h][dh][l'],
    // columns group-permuted: stored group G holds T group sigma_G(G).
    unsigned short* T = LB;                // 256 x 68 u16 = 34.8 KB (loop ended with barrier)
#pragma unroll
    for (int nt = 0; nt < 4; ++nt) {
      const int d0 = wv * 64 + nt * 16 + fg * 4;
      const f32x4 bb = *(const f32x4*)(bias + d0);
#pragma unroll
      for (int mt = 0; mt < 4; ++mt)
#pragma unroll
        for (int r = 0; r < 4; ++r)
          T[(d0 + r) * 68 + mt * 16 + fr] = f2b(acc[nt][mt][r] + bb[r]);
    }
    __syncthreads();
    const int d = tid;
    unsigned short* dst = Vt + ((size_t)(b * H_ + (d >> 5)) * 32 + (d & 31)) * L_ + ll0;
#pragma unroll
    for (int G = 0; G < 16; ++G) {
      const int S = (G & 8) | ((G & 1) << 2) | ((G >> 1) & 3);
      *(u16x4*)(dst + G * 4) = *(const u16x4*)(T + d * 68 + S * 4);
    }
  }
}

// ---------------- Q-side projections: Qa = qc+qp, Qb = qc+qp+qs (scaled) --------
__global__ __launch_bounds__(256, 2) void qproj_k(
    const float* __restrict__ xp, const float* __restrict__ xq, const float* __restrict__ xs,
    const unsigned short* __restrict__ Wq,
    const float* __restrict__ bqp, const float* __restrict__ bqc, const float* __restrict__ bqs,
    unsigned short* __restrict__ Qcat)
{
  __shared__ __align__(16) unsigned short Al[2][64 * 64];
  __shared__ __align__(16) unsigned short Bl[2][256 * 64];
  const int tid = threadIdx.x, lane = tid & 63, wv = tid >> 6;
  const int fr = lane & 15, fg = lane >> 4;
  const int b = blockIdx.x / 5, n0 = (blockIdx.x % 5) * 64;
  const float* Ax[3] = {xp, xq, xs};

  const int sr = tid >> 2, sc = (tid & 3) * 16;
  const int ag = sc >> 3;
  const bool arow_ok = (n0 + sr) < N_;

  f32x4 acc[16] = {};

  auto stageB = [&](int step, int buf) {
    const char* bsrc = (const char*)Wq + (size_t)step * 32768;
    char* bdst = (char*)&Bl[buf][0];
#pragma unroll
    for (int c = 0; c < 8; ++c) {
      const int off = c * 4096 + wv * 1024 + lane * 16;
      gload_lds16(bsrc + off, bdst + off);
    }
  };
  auto stageA_load = [&](int step, f32x4* ar) {
    const int i = step >> 2, kt = step & 3;
    if (arow_ok) {
      const float* src = Ax[i] + ((size_t)b * N_ + n0 + sr) * C_ + kt * 64 + sc;
#pragma unroll
      for (int j = 0; j < 4; ++j) ar[j] = *(const f32x4*)(src + j * 4);
    } else {
#pragma unroll
      for (int j = 0; j < 4; ++j) ar[j] = (f32x4){0.f, 0.f, 0.f, 0.f};
    }
  };
  auto stageA_write = [&](int buf, const f32x4* ar) {
    unsigned short* base = &Al[buf][sr * 64];
    bf8_t v0, v1;
#pragma unroll
    for (int j = 0; j < 4; ++j) {
      v0[j] = (short)f2b(ar[0][j]); v0[4 + j] = (short)f2b(ar[1][j]);
      v1[j] = (short)f2b(ar[2][j]); v1[4 + j] = (short)f2b(ar[3][j]);
    }
    *(bf8_t*)(base + ((ag ^ (sr & 7)) * 8))       = v0;
    *(bf8_t*)(base + (((ag | 1) ^ (sr & 7)) * 8)) = v1;
  };

  {  // prologue
    f32x4 a0[4];
    stageA_load(0, a0);
    stageB(0, 0);
    stageA_write(0, a0);
  }
  __syncthreads();

  int cur = 0;
  const int xrow = wv * 16 + fr;
  const int n_out = n0 + wv * 16 + fr;
  const bool ok = n_out < N_;
  for (int step = 0; step < 12; ++step) {
    const int nxt = cur ^ 1;
    f32x4 arn[4];
    if (step < 11) {
      stageA_load(step + 1, arn);
      stageB(step + 1, nxt);
    }
    const unsigned short* Ab = &Al[cur][0];
    const unsigned short* Bb = &Bl[cur][0];
#pragma unroll
    for (int kh = 0; kh < 2; ++kh) {
      const int gxx = (4 * kh + fg) ^ (fr & 7);
      bf8_t xf = *(const bf8_t*)(Ab + xrow * 64 + gxx * 8);
#pragma unroll
      for (int nt = 0; nt < 16; ++nt) {
        bf8_t wf = *(const bf8_t*)(Bb + (nt * 16 + fr) * 64 + gxx * 8);
        acc[nt] = __builtin_amdgcn_mfma_f32_16x16x32_bf16(wf, xf, acc[nt], 0, 0, 0);
      }
    }
    if (step == 7 || step == 11) {
      const int off = (step == 7) ? 0 : 32;
#pragma unroll
      for (int nt = 0; nt < 16; ++nt) {
        const int d0 = nt * 16 + fg * 4;
        f32x4 bb = *(const f32x4*)(bqp + d0) + *(const f32x4*)(bqc + d0);
        if (step == 11) bb += *(const f32x4*)(bqs + d0);
        u16x4 v;
#pragma unroll
        for (int r = 0; r < 4; ++r) v[r] = ok ? f2b((acc[nt][r] + bb[r]) * SCALE) : (unsigned short)0;
        *(u16x4*)(Qcat + ((size_t)(b * H_ + (d0 >> 5)) * NPAD + n_out) * 64 + off + (d0 & 31)) = v;
      }
    }
    if (step < 11) stageA_write(nxt, arn);
    __syncthreads();
    cur = nxt;
  }
}

// ---------------- flash attention: swapped QK^T, lane-local softmax, reg-P PV ---
// K reg-staged into XOR-swizzled [64][32]-u16 LDS, single ds_read_b128 fragments.
// V pre-permuted (sigma_G in kvproj) -> PV fragment is a single aligned b128.
// Softmax denominator via ones-operand MFMA (sum on the matrix pipe).
__global__ __launch_bounds__(256, 5) void attn_k(
    const unsigned short* __restrict__ Qcat, const unsigned short* __restrict__ Kc,
    const unsigned short* __restrict__ Kp, const unsigned short* __restrict__ Vt,
    float* __restrict__ PO, float* __restrict__ PM, float* __restrict__ PLs)
{
  __shared__ __align__(16) unsigned short Kcl[2][64 * 32];   // 8 KB (swizzled 64-B rows)
  __shared__ __align__(16) unsigned short Kpl[2][64 * 32];   // 8 KB
  __shared__ __align__(16) unsigned short Vp[2][32][72];     // 9.2 KB
  const int x = blockIdx.x;
  const int qt = x >> 8;                 // / (B*H*SPL) = /256
  const int rem = x & 255;
  const int s = rem & (SPL_ - 1);
  const int h = (rem >> 2) & (H_ - 1);
  const int b = rem >> 5;
  const int n0 = qt * 64;
  const int tid = threadIdx.x, lane = tid & 63, wv = tid >> 6;
  const int fr = lane & 15, fg = lane >> 4;

  const unsigned short* Qb = Qcat + ((size_t)b * H_ + h) * NPAD * 64;
  bf8_t qf[2];
  {
    const int qrow = n0 + wv * 16 + fr;
    qf[0] = *(const bf8_t*)&Qb[(size_t)qrow * 64 + 8 * fg];
    qf[1] = *(const bf8_t*)&Qb[(size_t)qrow * 64 + 32 + 8 * fg];
  }
  bf8_t ones8;
#pragma unroll
  for (int j = 0; j < 8; ++j) ones8[j] = (short)0x3F80;   // bf16 1.0

  float m_r = -1e30f;                    // per-lane running max (q = fr)
  f32x4 o[2] = {};                       // O^T[d = df*16+fg*4+r][q = fr]
  f32x4 o2 = {};                         // denominator: every element = sum_k P[q]

  const unsigned short* KcB = Kc + ((size_t)b * H_ + h) * L_ * 32;
  const unsigned short* KpB = Kp + ((size_t)b * H_ + h) * L_ * 32;
  const unsigned short* VB  = Vt + ((size_t)b * H_ + h) * 32 * (size_t)L_;

  const int sl = tid >> 2, sg = tid & 3;        // K staging: row, 8-u16 granule
  const int sgx = (sg ^ (sl & 3)) * 8;          // swizzled write offset in row
  const int vd = tid >> 3, vc = (tid & 7) * 8;  // V staging
  const int kgx = (fg ^ (fr & 3)) * 8;          // swizzled read offset (row&3 = fr&3)

  auto loadK = [&](int t, bf8_t* kc2, bf8_t* kp2) {
    const size_t off = ((size_t)(t * 64 + sl)) * 32 + sg * 8;
    *kc2 = *(const bf8_t*)(KcB + off);
    *kp2 = *(const bf8_t*)(KpB + off);
  };

  const int t0 = s * TPS_, t1 = t0 + TPS_;
  bf8_t kcr, kpr, vreg;
  loadK(t0, &kcr, &kpr);
  vreg = *(const bf8_t*)(VB + (size_t)vd * L_ + t0 * 64 + vc);

  int cur = 0;
  for (int t = t0; t < t1; ++t) {
    {  // stage K (swizzled b128) + V; waits only on regs loaded 1 phase ago
      *(bf8_t*)&Kcl[cur][sl * 32 + sgx] = kcr;
      *(bf8_t*)&Kpl[cur][sl * 32 + sgx] = kpr;
      *(bf8_t*)&Vp[cur][vd][vc] = vreg;
    }
    __syncthreads();                       // nothing outstanding: drain is free
    if (t + 1 < t1) {                      // issue t+1 loads; land during compute(t)
      loadK(t + 1, &kcr, &kpr);
      vreg = *(const bf8_t*)(VB + (size_t)vd * L_ + (t + 1) * 64 + vc);
    }
    // ---- scores S^T (swapped operands), single-b128 fragment reads ----
    f32x4 sc[4] = {};
#pragma unroll
    for (int nf = 0; nf < 4; ++nf) {
      const int ro = (nf * 16 + fr) * 32 + kgx;
      bf8_t kf0 = *(const bf8_t*)&Kcl[cur][ro];
      bf8_t kf1 = *(const bf8_t*)&Kpl[cur][ro];
      sc[nf] = __builtin_amdgcn_mfma_f32_16x16x32_bf16(kf0, qf[0], sc[nf], 0, 0, 0);
      sc[nf] = __builtin_amdgcn_mfma_f32_16x16x32_bf16(kf1, qf[1], sc[nf], 0, 0, 0);
    }
    // ---- lane-local online softmax (q = fr), defer-max (T13) ----
    float mx = fmaxf(fmaxf(sc[0][0], sc[0][1]), fmaxf(sc[0][2], sc[0][3]));
#pragma unroll
    for (int nf = 1; nf < 4; ++nf)
      mx = fmaxf(mx, fmaxf(fmaxf(sc[nf][0], sc[nf][1]), fmaxf(sc[nf][2], sc[nf][3])));
    mx = fmaxf(mx, __shfl_xor(mx, 16));
    mx = fmaxf(mx, __shfl_xor(mx, 32));
    if (!__all(mx <= m_r + 8.f)) {        // rescale only when max grew materially
      const float mnew = fmaxf(m_r, mx);
      const float corr = exp2f(m_r - mnew);
#pragma unroll
      for (int r = 0; r < 4; ++r) { o[0][r] *= corr; o[1][r] *= corr; o2[r] *= corr; }
      m_r = mnew;
    }
#pragma unroll
    for (int nf = 0; nf < 4; ++nf)
#pragma unroll
      for (int r = 0; r < 4; ++r)
        sc[nf][r] = exp2f(sc[nf][r] - m_r);
    // ---- pack P to bf16 (lane-local; slot order matches V layout) ----
    unsigned pw[8];
#pragma unroll
    for (int nf = 0; nf < 4; ++nf) {
      pw[2 * nf]     = cvt_pk_bf16(sc[nf][0], sc[nf][1]);
      pw[2 * nf + 1] = cvt_pk_bf16(sc[nf][2], sc[nf][3]);
    }
    // ---- PV + denominator: O^T += V^T . P^T ;  o2 += 1 . P^T ----
#pragma unroll
    for (int kh = 0; kh < 2; ++kh) {
      union { unsigned u[4]; bf8_t v; } pu;
      pu.u[0] = pw[4 * kh];     pu.u[1] = pw[4 * kh + 1];
      pu.u[2] = pw[4 * kh + 2]; pu.u[3] = pw[4 * kh + 3];
      const bf8_t pf = pu.v;
      o2 = __builtin_amdgcn_mfma_f32_16x16x32_bf16(ones8, pf, o2, 0, 0, 0);
#pragma unroll
      for (int df = 0; df < 2; ++df) {
        bf8_t vf = *(const bf8_t*)(&Vp[cur][df * 16 + fr][0] + kh * 32 + fg * 8);
        o[df] = __builtin_amdgcn_mfma_f32_16x16x32_bf16(vf, pf, o[df], 0, 0, 0);
      }
    }
    cur ^= 1;
  }
  // ---- epilogue: PO[rec][q][d], PM/PLs per q ----
  const int rec = (((b * H_) + h) * QT_ + qt) * SPL_ + s;
  const int q = wv * 16 + fr;
  if (fg == 0) {
    PM [rec * 64 + q] = m_r;
    PLs[rec * 64 + q] = o2[0];
  }
#pragma unroll
  for (int df = 0; df < 2; ++df)
    *(f32x4*)(PO + ((size_t)rec * 64 + q) * 32 + df * 16 + fg * 4) = o[df];
}

// ---------------- combine splits -> aout (bf16) --------------------------------
__global__ __launch_bounds__(256) void combine_k(
    const float* __restrict__ PO, const float* __restrict__ PM, const float* __restrict__ PLs,
    unsigned short* __restrict__ aout)
{
  const int qt = blockIdx.x, h = blockIdx.y, b = blockIdx.z;
  const int tid = threadIdx.x;
  const int row = tid >> 2, dh0 = (tid & 3) * 8;
  const int rec0 = (((b * H_) + h) * QT_ + qt) * SPL_;
  float m[SPL_], w[SPL_];
  float M = -1e30f;
#pragma unroll
  for (int s = 0; s < SPL_; ++s) { m[s] = PM[(rec0 + s) * 64 + row]; M = fmaxf(M, m[s]); }
  float denom = 0.f;
#pragma unroll
  for (int s = 0; s < SPL_; ++s) {
    w[s] = exp2f(m[s] - M);
    denom += w[s] * PLs[(rec0 + s) * 64 + row];
  }
  float num[8] = {};
#pragma unroll
  for (int s = 0; s < SPL_; ++s) {
    const float* po = PO + ((size_t)(rec0 + s) * 64 + row) * 32 + dh0;
    f32x4 a = *(const f32x4*)po;
    f32x4 c = *(const f32x4*)(po + 4);
#pragma unroll
    for (int j = 0; j < 4; ++j) { num[j] += w[s] * a[j]; num[4 + j] += w[s] * c[j]; }
  }
  const int n = qt * 64 + row;
  if (n < N_) {
    const float inv = 1.f / denom;
    bf8_t v;
#pragma unroll
    for (int j = 0; j < 8; ++j) v[j] = (short)f2b(num[j] * inv);
    *(bf8_t*)(aout + ((size_t)b * NPAD + n) * C_ + h * 32 + dh0) = v;
  }
}

// ---------------- output projection + bias + residual ---------------------------
__global__ __launch_bounds__(256) void oproj_k(
    const unsigned short* __restrict__ aout, const float* __restrict__ Wo,
    const float* __restrict__ bo, const float* __restrict__ query,
    float* __restrict__ out)
{
  __shared__ __align__(16) unsigned short Al[64][72];
  __shared__ __align__(16) unsigned short Bl[64][72];
  const int b = blockIdx.z, n0 = blockIdx.y * 64, d0 = blockIdx.x * 64;
  const int tid = threadIdx.x, lane = tid & 63, wv = tid >> 6;
  const int wm = wv >> 1, wn = wv & 1;
  const int sr = tid >> 2, sc = (tid & 3) * 16;
  const int fr = lane & 15, fg = lane >> 4;
  f32x4 acc[2][2] = {};

  for (int kt = 0; kt < 4; ++kt) {
    const int k0 = kt * 64;
    {
      const unsigned short* src = aout + ((size_t)b * NPAD + n0 + sr) * C_ + k0 + sc;
      *(bf8_t*)&Al[sr][sc]     = *(const bf8_t*)src;
      *(bf8_t*)&Al[sr][sc + 8] = *(const bf8_t*)(src + 8);
    }
    stage_cvt16(&Bl[sr][sc], Wo + (size_t)(d0 + sr) * C_ + k0 + sc);
    __syncthreads();
#pragma unroll
    for (int kh = 0; kh < 2; ++kh) {
      const int ko = kh * 32 + 8 * fg;
      bf8_t af[2], bq[2];
#pragma unroll
      for (int m = 0; m < 2; ++m) {
        af[m] = *(const bf8_t*)&Al[wm * 32 + m * 16 + fr][ko];
        bq[m] = *(const bf8_t*)&Bl[wn * 32 + m * 16 + fr][ko];
      }
#pragma unroll
      for (int m = 0; m < 2; ++m)
#pragma unroll
        for (int n = 0; n < 2; ++n)
          acc[m][n] = __builtin_amdgcn_mfma_f32_16x16x32_bf16(af[m], bq[n], acc[m][n], 0, 0, 0);
    }
    __syncthreads();
  }
#pragma unroll
  for (int m = 0; m < 2; ++m)
#pragma unroll
    for (int nn = 0; nn < 2; ++nn) {
      const int d = d0 + wn * 32 + nn * 16 + fr;
      const float bb = bo[d];
#pragma unroll
      for (int r = 0; r < 4; ++r) {
        const int n = n0 + wm * 32 + m * 16 + fg * 4 + r;
        if (n < N_) {
          const size_t gi = ((size_t)b * N_ + n) * C_ + d;
          out[gi] = acc[m][nn][r] + bb + query[gi];
        }
      }
    }
}

extern "C" void kernel_launch(void* const* d_in, const int* in_sizes, int n_in,
                              void* d_out, int out_size, void* d_ws, size_t ws_size,
                              hipStream_t stream)
{
  const float* query = (const float*)d_in[0];
  const float* key   = (const float*)d_in[1];
  const float* value = (const float*)d_in[2];
  const float* qpos  = (const float*)d_in[3];
  const float* kpos  = (const float*)d_in[4];
  const float* qsine = (const float*)d_in[5];
  const float* Wqc = (const float*)d_in[6];  const float* bqc = (const float*)d_in[7];
  const float* Wqp = (const float*)d_in[8];  const float* bqp = (const float*)d_in[9];
  const float* Wqs = (const float*)d_in[10]; const float* bqs = (const float*)d_in[11];
  const float* Wkc = (const float*)d_in[12]; const float* bkc = (const float*)d_in[13];
  const float* Wkp = (const float*)d_in[14]; const float* bkp = (const float*)d_in[15];
  const float* Wv  = (const float*)d_in[16]; const float* bv  = (const float*)d_in[17];
  const float* Wo  = (const float*)d_in[18]; const float* bo  = (const float*)d_in[19];

  // workspace layout
  const size_t qcat_b = (size_t)B_ * H_ * NPAD * 64 * 2;             //  2.62 MB
  const size_t kc_b   = (size_t)B_ * H_ * L_ * 32 * 2;               // 16.78 MB
  const size_t kp_b   = kc_b;                                        // 16.78 MB
  const size_t vt_b   = kc_b;                                        // 16.78 MB
  const size_t aout_b = (size_t)B_ * NPAD * C_ * 2;                  //  1.31 MB
  const size_t nrec   = (size_t)B_ * H_ * QT_ * SPL_;                // 1280
  const size_t po_b   = nrec * 64 * 32 * 4;                          // 10.49 MB
  const size_t pm_b   = nrec * 64 * 4;
  const size_t pl_b   = nrec * 64 * 4;
  const size_t wsw_b  = (size_t)24 * 256 * 64 * 2;                   //  0.79 MB (Wq 12x32KB + Wk 24x16KB)
  if (ws_size < qcat_b + kc_b + kp_b + vt_b + aout_b + po_b + pm_b + pl_b + wsw_b) return;
  char* ws = (char*)d_ws;
  unsigned short* Qcat = (unsigned short*)(ws);
  unsigned short* Kc   = (unsigned short*)(ws + qcat_b);
  unsigned short* Kp   = (unsigned short*)(ws + qcat_b + kc_b);
  unsigned short* Vt   = (unsigned short*)(ws + qcat_b + kc_b + kp_b);
  unsigned short* aout = (unsigned short*)(ws + qcat_b + kc_b + kp_b + vt_b);
  float* PO  = (float*)(ws + qcat_b + kc_b + kp_b + vt_b + aout_b);
  float* PM  = (float*)(ws + qcat_b + kc_b + kp_b + vt_b + aout_b + po_b);
  float* PLs = (float*)(ws + qcat_b + kc_b + kp_b + vt_b + aout_b + po_b + pm_b);
  unsigned short* Wq = (unsigned short*)(ws + qcat_b + kc_b + kp_b + vt_b + aout_b + po_b + pm_b + pl_b);
  unsigned short* Wk = Wq + (size_t)12 * 16384;      // after 12 x 32 KB q-slots
  float* out = (float*)d_out;

  wcvt_all_k<<<dim3(8, 3),                256, 0, stream>>>(Wkp, Wkc, Wv, Wqp, Wqc, Wqs, Wk, Wq);
  qproj_k  <<<dim3(B_ * QT_),             256, 0, stream>>>(qpos, query, qsine, Wq, bqp, bqc, bqs, Qcat);
  kvproj_k <<<dim3(512, 3),               256, 0, stream>>>(kpos, key, value, Wk, bkp, bkc, bv, Kc, Kp, Vt);
  attn_k   <<<dim3(QT_ * SPL_ * B_ * H_), 256, 0, stream>>>(Qcat, Kc, Kp, Vt, PO, PM, PLs);
  combine_k<<<dim3(QT_, 8, 8),            256, 0, stream>>>(PO, PM, PLs, aout);
  oproj_k  <<<dim3(4, QT_, 8),            256, 0, stream>>>(aout, Wo, bo, query, out);
}

// Round 22
// 123.318 us; speedup vs baseline: 1.0850x; 1.0850x over previous
//
#include <hip/hip_runtime.h>
#include <hip/hip_bf16.h>

using bf8_t = __attribute__((ext_vector_type(8))) short;
using bf4_t = __attribute__((ext_vector_type(4))) short;
using u16x4 = __attribute__((ext_vector_type(4))) unsigned short;
using f32x4 = __attribute__((ext_vector_type(4))) float;

constexpr int B_   = 8;
constexpr int N_   = 300;
constexpr int L_   = 4096;
constexpr int C_   = 256;
constexpr int H_   = 8;
constexpr int NPAD = 320;          // 5 row-tiles of 64
constexpr int QT_  = 5;            // q tiles of 64
constexpr int SPL_ = 4;            // KV splits; B*H*SPL = 256 = 0 mod 8 (XCD-aligned)
constexpr int TPS_ = 16;           // 64-key tiles per split
// scale folded with log2(e) so softmax uses native exp2 (v_exp_f32)
constexpr float SCALE = 0.18033688011112042f;   // (2*32)^-0.5 * log2(e)

__device__ __forceinline__ unsigned short f2b(float f) {
  unsigned u = __float_as_uint(f);
  u += 0x7FFFu + ((u >> 16) & 1u);          // RNE
  return (unsigned short)(u >> 16);
}

// convert 16 contiguous f32 -> 16 bf16 into LDS (dst 16B-aligned)
__device__ __forceinline__ void stage_cvt16(unsigned short* dst, const float* src) {
#pragma unroll
  for (int half = 0; half < 2; ++half) {
    f32x4 x0 = *(const f32x4*)(src + half * 8);
    f32x4 x1 = *(const f32x4*)(src + half * 8 + 4);
    bf8_t v;
#pragma unroll
    for (int j = 0; j < 4; ++j) { v[j] = (short)f2b(x0[j]); v[4 + j] = (short)f2b(x1[j]); }
    *(bf8_t*)(dst + half * 8) = v;
  }
}

__device__ __forceinline__ void gload_lds16(const void* g, void* l) {
  __builtin_amdgcn_global_load_lds(
      (const __attribute__((address_space(1))) unsigned int*)g,
      (__attribute__((address_space(3))) unsigned int*)l, 16, 0, 0);
}

__device__ __forceinline__ unsigned cvt_pk_bf16(float lo, float hi) {
  unsigned r;
  asm("v_cvt_pk_bf16_f32 %0, %1, %2" : "=v"(r) : "v"(lo), "v"(hi));
  return r;
}

// ---------------- weight pre-convert (single launch, both layouts) --------------
// kv family (W0..W2 -> Wk): BK=32 tiles, slot i*8+x, XOR(d&3).
// q  family (W3..W5 -> Wq): BK=64 tiles, slot i*4+x (x<4 only), XOR(d&7).
__global__ __launch_bounds__(256) void wcvt_all_k(
    const float* __restrict__ W0, const float* __restrict__ W1, const float* __restrict__ W2,
    const float* __restrict__ W3, const float* __restrict__ W4, const float* __restrict__ W5,
    unsigned short* __restrict__ Wk, unsigned short* __restrict__ Wq)
{
  const float* Wkv[3] = {W0, W1, W2};
  const float* Wqq[3] = {W3, W4, W5};
  const int x = blockIdx.x, i = blockIdx.y;        // x in 0..7, i in 0..2
  const int d = threadIdx.x;
  {  // kv: 32-wide tile x
    const float* src = Wkv[i] + (size_t)d * C_ + x * 32;
    unsigned short* dst = Wk + ((size_t)(i * 8 + x) * 256 + d) * 32;
#pragma unroll
    for (int g = 0; g < 4; ++g) {
      f32x4 a = *(const f32x4*)(src + g * 8);
      f32x4 b = *(const f32x4*)(src + g * 8 + 4);
      bf8_t v;
#pragma unroll
      for (int j = 0; j < 4; ++j) { v[j] = (short)f2b(a[j]); v[4 + j] = (short)f2b(b[j]); }
      *(bf8_t*)(dst + (g ^ (d & 3)) * 8) = v;
    }
  }
  if (x < 4) {  // q: 64-wide tile x
    const float* src = Wqq[i] + (size_t)d * C_ + x * 64;
    unsigned short* dst = Wq + ((size_t)(i * 4 + x) * 256 + d) * 64;
#pragma unroll
    for (int g = 0; g < 8; ++g) {
      f32x4 a = *(const f32x4*)(src + g * 8);
      f32x4 b = *(const f32x4*)(src + g * 8 + 4);
      bf8_t v;
#pragma unroll
      for (int j = 0; j < 4; ++j) { v[j] = (short)f2b(a[j]); v[4 + j] = (short)f2b(b[j]); }
      *(bf8_t*)(dst + (g ^ (d & 7)) * 8) = v;
    }
  }
}

// ---------------- K-side projections: independent per (row-chunk, i) ------------
// (round-11 version: LDS-staged, 40 KB, BK=32, 8 steps, 2-D wave split)
// V written with group-permuted columns sigma_G so attn PV reads are single b128.
__global__ __launch_bounds__(256, 4) void kvproj_k(
    const float* __restrict__ xp, const float* __restrict__ xk, const float* __restrict__ xv,
    const unsigned short* __restrict__ Wk,
    const float* __restrict__ bkp, const float* __restrict__ bkc, const float* __restrict__ bv,
    unsigned short* __restrict__ Kc, unsigned short* __restrict__ Kp, unsigned short* __restrict__ Vt)
{
  __shared__ __align__(16) unsigned short LB[20480];   // 40 KB: A@0/2048, B@4096/12288; T alias
  const int tid = threadIdx.x, lane = tid & 63, wv = tid >> 6;
  const int fr = lane & 15, fg = lane >> 4;
  const int i = blockIdx.y;
  const int row0 = blockIdx.x * 64;
  const int b = row0 >> 12, ll0 = row0 & (L_ - 1);
  const float* X    = (i == 0) ? xp  : (i == 1) ? xk  : xv;
  const float* bias = (i == 0) ? bkp : (i == 1) ? bkc : bv;

  const int ar = tid >> 2, ac = tid & 3;               // A-stage: row, granule
  const int agx = (ac ^ (ar & 3)) * 8;

  f32x4 acc[4][4] = {};

  const unsigned short* Wi = Wk + (size_t)i * 8 * 8192;

  auto stageB = [&](int step, int buf) {
    const char* src = (const char*)(Wi + step * 8192);
    char* dst = (char*)(LB + 4096 + buf * 8192);
#pragma unroll
    for (int c = 0; c < 4; ++c) {
      const int off = c * 4096 + tid * 16;
      gload_lds16(src + off, dst + off);
    }
  };
  auto stageA_load = [&](int step, f32x4* arg) {
    const float* s = X + (size_t)(row0 + ar) * C_ + step * 32 + ac * 8;
    arg[0] = *(const f32x4*)s;
    arg[1] = *(const f32x4*)(s + 4);
  };
  auto stageA_write = [&](int buf, const f32x4* arg) {
    bf8_t v;
#pragma unroll
    for (int j = 0; j < 4; ++j) { v[j] = (short)f2b(arg[0][j]); v[4 + j] = (short)f2b(arg[1][j]); }
    *(bf8_t*)(LB + buf * 2048 + ar * 32 + agx) = v;
  };

  {  // prologue
    f32x4 a0[2];
    stageA_load(0, a0);
    stageB(0, 0);
    stageA_write(0, a0);
  }
  __syncthreads();

  int cur = 0;
  const int gx = (fg ^ (fr & 3)) * 8;
  for (int step = 0; step < 8; ++step) {
    const int nxt = cur ^ 1;
    f32x4 arn[2];
    if (step < 7) {
      stageA_load(step + 1, arn);
      stageB(step + 1, nxt);
    }
    const unsigned short* Ab = LB + cur * 2048;
    const unsigned short* Bb = LB + 4096 + cur * 8192;
    bf8_t xf[4];
#pragma unroll
    for (int mt = 0; mt < 4; ++mt)
      xf[mt] = *(const bf8_t*)(Ab + (mt * 16 + fr) * 32 + gx);
#pragma unroll
    for (int nt = 0; nt < 4; ++nt) {
      bf8_t wf = *(const bf8_t*)(Bb + (wv * 64 + nt * 16 + fr) * 32 + gx);
#pragma unroll
      for (int mt = 0; mt < 4; ++mt)
        acc[nt][mt] = __builtin_amdgcn_mfma_f32_16x16x32_bf16(wf, xf[mt], acc[nt][mt], 0, 0, 0);
    }
    if (step < 7) stageA_write(nxt, arn);
    __syncthreads();
    cur = nxt;
  }

  if (i < 2) {
    unsigned short* outp = (i == 0) ? Kp : Kc;
#pragma unroll
    for (int nt = 0; nt < 4; ++nt) {
      const int d0 = wv * 64 + nt * 16 + fg * 4;
      const f32x4 bb = *(const f32x4*)(bias + d0);
      const int h = d0 >> 5, dh = d0 & 31;
#pragma unroll
      for (int mt = 0; mt < 4; ++mt) {
        const int l = ll0 + mt * 16 + fr;
        u16x4 v;
#pragma unroll
        for (int r = 0; r < 4; ++r) v[r] = f2b(acc[nt][mt][r] + bb[r]);
        *(u16x4*)(outp + ((size_t)(b * H_ + h) * L_ + l) * 32 + dh) = v;
      }
    }
  } else {
    // V: transpose through LDS (row stride 68 u16) -> Vt[b][h][dh][l'],
    // columns group-permuted: stored group G holds T group sigma_G(G).
    unsigned short* T = LB;                // 256 x 68 u16 = 34.8 KB (loop ended with barrier)
#pragma unroll
    for (int nt = 0; nt < 4; ++nt) {
      const int d0 = wv * 64 + nt * 16 + fg * 4;
      const f32x4 bb = *(const f32x4*)(bias + d0);
#pragma unroll
      for (int mt = 0; mt < 4; ++mt)
#pragma unroll
        for (int r = 0; r < 4; ++r)
          T[(d0 + r) * 68 + mt * 16 + fr] = f2b(acc[nt][mt][r] + bb[r]);
    }
    __syncthreads();
    const int d = tid;
    unsigned short* dst = Vt + ((size_t)(b * H_ + (d >> 5)) * 32 + (d & 31)) * L_ + ll0;
#pragma unroll
    for (int G = 0; G < 16; ++G) {
      const int S = (G & 8) | ((G & 1) << 2) | ((G >> 1) & 3);
      *(u16x4*)(dst + G * 4) = *(const u16x4*)(T + d * 68 + S * 4);
    }
  }
}

// ---------------- Q-side projections: Qa = qc+qp, Qb = qc+qp+qs (scaled) --------
__global__ __launch_bounds__(256, 2) void qproj_k(
    const float* __restrict__ xp, const float* __restrict__ xq, const float* __restrict__ xs,
    const unsigned short* __restrict__ Wq,
    const float* __restrict__ bqp, const float* __restrict__ bqc, const float* __restrict__ bqs,
    unsigned short* __restrict__ Qcat)
{
  __shared__ __align__(16) unsigned short Al[2][64 * 64];
  __shared__ __align__(16) unsigned short Bl[2][256 * 64];
  const int tid = threadIdx.x, lane = tid & 63, wv = tid >> 6;
  const int fr = lane & 15, fg = lane >> 4;
  const int b = blockIdx.x / 5, n0 = (blockIdx.x % 5) * 64;
  const float* Ax[3] = {xp, xq, xs};

  const int sr = tid >> 2, sc = (tid & 3) * 16;
  const int ag = sc >> 3;
  const bool arow_ok = (n0 + sr) < N_;

  f32x4 acc[16] = {};

  auto stageB = [&](int step, int buf) {
    const char* bsrc = (const char*)Wq + (size_t)step * 32768;
    char* bdst = (char*)&Bl[buf][0];
#pragma unroll
    for (int c = 0; c < 8; ++c) {
      const int off = c * 4096 + wv * 1024 + lane * 16;
      gload_lds16(bsrc + off, bdst + off);
    }
  };
  auto stageA_load = [&](int step, f32x4* ar) {
    const int i = step >> 2, kt = step & 3;
    if (arow_ok) {
      const float* src = Ax[i] + ((size_t)b * N_ + n0 + sr) * C_ + kt * 64 + sc;
#pragma unroll
      for (int j = 0; j < 4; ++j) ar[j] = *(const f32x4*)(src + j * 4);
    } else {
#pragma unroll
      for (int j = 0; j < 4; ++j) ar[j] = (f32x4){0.f, 0.f, 0.f, 0.f};
    }
  };
  auto stageA_write = [&](int buf, const f32x4* ar) {
    unsigned short* base = &Al[buf][sr * 64];
    bf8_t v0, v1;
#pragma unroll
    for (int j = 0; j < 4; ++j) {
      v0[j] = (short)f2b(ar[0][j]); v0[4 + j] = (short)f2b(ar[1][j]);
      v1[j] = (short)f2b(ar[2][j]); v1[4 + j] = (short)f2b(ar[3][j]);
    }
    *(bf8_t*)(base + ((ag ^ (sr & 7)) * 8))       = v0;
    *(bf8_t*)(base + (((ag | 1) ^ (sr & 7)) * 8)) = v1;
  };

  {  // prologue
    f32x4 a0[4];
    stageA_load(0, a0);
    stageB(0, 0);
    stageA_write(0, a0);
  }
  __syncthreads();

  int cur = 0;
  const int xrow = wv * 16 + fr;
  const int n_out = n0 + wv * 16 + fr;
  const bool ok = n_out < N_;
  for (int step = 0; step < 12; ++step) {
    const int nxt = cur ^ 1;
    f32x4 arn[4];
    if (step < 11) {
      stageA_load(step + 1, arn);
      stageB(step + 1, nxt);
    }
    const unsigned short* Ab = &Al[cur][0];
    const unsigned short* Bb = &Bl[cur][0];
#pragma unroll
    for (int kh = 0; kh < 2; ++kh) {
      const int gxx = (4 * kh + fg) ^ (fr & 7);
      bf8_t xf = *(const bf8_t*)(Ab + xrow * 64 + gxx * 8);
#pragma unroll
      for (int nt = 0; nt < 16; ++nt) {
        bf8_t wf = *(const bf8_t*)(Bb + (nt * 16 + fr) * 64 + gxx * 8);
        acc[nt] = __builtin_amdgcn_mfma_f32_16x16x32_bf16(wf, xf, acc[nt], 0, 0, 0);
      }
    }
    if (step == 7 || step == 11) {
      const int off = (step == 7) ? 0 : 32;
#pragma unroll
      for (int nt = 0; nt < 16; ++nt) {
        const int d0 = nt * 16 + fg * 4;
        f32x4 bb = *(const f32x4*)(bqp + d0) + *(const f32x4*)(bqc + d0);
        if (step == 11) bb += *(const f32x4*)(bqs + d0);
        u16x4 v;
#pragma unroll
        for (int r = 0; r < 4; ++r) v[r] = ok ? f2b((acc[nt][r] + bb[r]) * SCALE) : (unsigned short)0;
        *(u16x4*)(Qcat + ((size_t)(b * H_ + (d0 >> 5)) * NPAD + n_out) * 64 + off + (d0 & 31)) = v;
      }
    }
    if (step < 11) stageA_write(nxt, arn);
    __syncthreads();
    cur = nxt;
  }
}

// ---------------- flash attention: swapped QK^T, lane-local softmax, reg-P PV ---
// K reg-staged into XOR-swizzled [64][32]-u16 LDS, single ds_read_b128 fragments.
// V pre-permuted (sigma_G in kvproj) -> PV fragment is a single aligned b128.
// Softmax denominator via ones-operand MFMA (sum on the matrix pipe).
__global__ __launch_bounds__(256, 5) void attn_k(
    const unsigned short* __restrict__ Qcat, const unsigned short* __restrict__ Kc,
    const unsigned short* __restrict__ Kp, const unsigned short* __restrict__ Vt,
    float* __restrict__ PO, float* __restrict__ PM, float* __restrict__ PLs)
{
  __shared__ __align__(16) unsigned short Kcl[2][64 * 32];   // 8 KB (swizzled 64-B rows)
  __shared__ __align__(16) unsigned short Kpl[2][64 * 32];   // 8 KB
  __shared__ __align__(16) unsigned short Vp[2][32][72];     // 9.2 KB
  const int x = blockIdx.x;
  const int qt = x >> 8;                 // / (B*H*SPL) = /256
  const int rem = x & 255;
  const int s = rem & (SPL_ - 1);
  const int h = (rem >> 2) & (H_ - 1);
  const int b = rem >> 5;
  const int n0 = qt * 64;
  const int tid = threadIdx.x, lane = tid & 63, wv = tid >> 6;
  const int fr = lane & 15, fg = lane >> 4;

  const unsigned short* Qb = Qcat + ((size_t)b * H_ + h) * NPAD * 64;
  bf8_t qf[2];
  {
    const int qrow = n0 + wv * 16 + fr;
    qf[0] = *(const bf8_t*)&Qb[(size_t)qrow * 64 + 8 * fg];
    qf[1] = *(const bf8_t*)&Qb[(size_t)qrow * 64 + 32 + 8 * fg];
  }
  bf8_t ones8;
#pragma unroll
  for (int j = 0; j < 8; ++j) ones8[j] = (short)0x3F80;   // bf16 1.0

  float m_r = -1e30f;                    // per-lane running max (q = fr)
  f32x4 o[2] = {};                       // O^T[d = df*16+fg*4+r][q = fr]
  f32x4 o2 = {};                         // denominator: every element = sum_k P[q]

  const unsigned short* KcB = Kc + ((size_t)b * H_ + h) * L_ * 32;
  const unsigned short* KpB = Kp + ((size_t)b * H_ + h) * L_ * 32;
  const unsigned short* VB  = Vt + ((size_t)b * H_ + h) * 32 * (size_t)L_;

  const int sl = tid >> 2, sg = tid & 3;        // K staging: row, 8-u16 granule
  const int sgx = (sg ^ (sl & 3)) * 8;          // swizzled write offset in row
  const int vd = tid >> 3, vc = (tid & 7) * 8;  // V staging
  const int kgx = (fg ^ (fr & 3)) * 8;          // swizzled read offset (row&3 = fr&3)

  auto loadK = [&](int t, bf8_t* kc2, bf8_t* kp2) {
    const size_t off = ((size_t)(t * 64 + sl)) * 32 + sg * 8;
    *kc2 = *(const bf8_t*)(KcB + off);
    *kp2 = *(const bf8_t*)(KpB + off);
  };

  const int t0 = s * TPS_, t1 = t0 + TPS_;
  bf8_t kcr, kpr, vreg;
  loadK(t0, &kcr, &kpr);
  vreg = *(const bf8_t*)(VB + (size_t)vd * L_ + t0 * 64 + vc);

  int cur = 0;
  for (int t = t0; t < t1; ++t) {
    {  // stage K (swizzled b128) + V; waits only on regs loaded 1 phase ago
      *(bf8_t*)&Kcl[cur][sl * 32 + sgx] = kcr;
      *(bf8_t*)&Kpl[cur][sl * 32 + sgx] = kpr;
      *(bf8_t*)&Vp[cur][vd][vc] = vreg;
    }
    __syncthreads();                       // nothing outstanding: drain is free
    if (t + 1 < t1) {                      // issue t+1 loads; land during compute(t)
      loadK(t + 1, &kcr, &kpr);
      vreg = *(const bf8_t*)(VB + (size_t)vd * L_ + (t + 1) * 64 + vc);
    }
    // ---- scores S^T (swapped operands), single-b128 fragment reads ----
    f32x4 sc[4] = {};
#pragma unroll
    for (int nf = 0; nf < 4; ++nf) {
      const int ro = (nf * 16 + fr) * 32 + kgx;
      bf8_t kf0 = *(const bf8_t*)&Kcl[cur][ro];
      bf8_t kf1 = *(const bf8_t*)&Kpl[cur][ro];
      sc[nf] = __builtin_amdgcn_mfma_f32_16x16x32_bf16(kf0, qf[0], sc[nf], 0, 0, 0);
      sc[nf] = __builtin_amdgcn_mfma_f32_16x16x32_bf16(kf1, qf[1], sc[nf], 0, 0, 0);
    }
    // ---- lane-local online softmax (q = fr), defer-max (T13) ----
    float mx = fmaxf(fmaxf(sc[0][0], sc[0][1]), fmaxf(sc[0][2], sc[0][3]));
#pragma unroll
    for (int nf = 1; nf < 4; ++nf)
      mx = fmaxf(mx, fmaxf(fmaxf(sc[nf][0], sc[nf][1]), fmaxf(sc[nf][2], sc[nf][3])));
    mx = fmaxf(mx, __shfl_xor(mx, 16));
    mx = fmaxf(mx, __shfl_xor(mx, 32));
    if (!__all(mx <= m_r + 8.f)) {        // rescale only when max grew materially
      const float mnew = fmaxf(m_r, mx);
      const float corr = exp2f(m_r - mnew);
#pragma unroll
      for (int r = 0; r < 4; ++r) { o[0][r] *= corr; o[1][r] *= corr; o2[r] *= corr; }
      m_r = mnew;
    }
#pragma unroll
    for (int nf = 0; nf < 4; ++nf)
#pragma unroll
      for (int r = 0; r < 4; ++r)
        sc[nf][r] = exp2f(sc[nf][r] - m_r);
    // ---- pack P to bf16 (lane-local; slot order matches V layout) ----
    unsigned pw[8];
#pragma unroll
    for (int nf = 0; nf < 4; ++nf) {
      pw[2 * nf]     = cvt_pk_bf16(sc[nf][0], sc[nf][1]);
      pw[2 * nf + 1] = cvt_pk_bf16(sc[nf][2], sc[nf][3]);
    }
    // ---- PV + denominator: O^T += V^T . P^T ;  o2 += 1 . P^T ----
#pragma unroll
    for (int kh = 0; kh < 2; ++kh) {
      union { unsigned u[4]; bf8_t v; } pu;
      pu.u[0] = pw[4 * kh];     pu.u[1] = pw[4 * kh + 1];
      pu.u[2] = pw[4 * kh + 2]; pu.u[3] = pw[4 * kh + 3];
      const bf8_t pf = pu.v;
      o2 = __builtin_amdgcn_mfma_f32_16x16x32_bf16(ones8, pf, o2, 0, 0, 0);
#pragma unroll
      for (int df = 0; df < 2; ++df) {
        bf8_t vf = *(const bf8_t*)(&Vp[cur][df * 16 + fr][0] + kh * 32 + fg * 8);
        o[df] = __builtin_amdgcn_mfma_f32_16x16x32_bf16(vf, pf, o[df], 0, 0, 0);
      }
    }
    cur ^= 1;
  }
  // ---- epilogue: PO[rec][q][d], PM/PLs per q ----
  const int rec = (((b * H_) + h) * QT_ + qt) * SPL_ + s;
  const int q = wv * 16 + fr;
  if (fg == 0) {
    PM [rec * 64 + q] = m_r;
    PLs[rec * 64 + q] = o2[0];
  }
#pragma unroll
  for (int df = 0; df < 2; ++df)
    *(f32x4*)(PO + ((size_t)rec * 64 + q) * 32 + df * 16 + fg * 4) = o[df];
}

// ---------------- combine splits -> aout (bf16) --------------------------------
__global__ __launch_bounds__(256) void combine_k(
    const float* __restrict__ PO, const float* __restrict__ PM, const float* __restrict__ PLs,
    unsigned short* __restrict__ aout)
{
  const int qt = blockIdx.x, h = blockIdx.y, b = blockIdx.z;
  const int tid = threadIdx.x;
  const int row = tid >> 2, dh0 = (tid & 3) * 8;
  const int rec0 = (((b * H_) + h) * QT_ + qt) * SPL_;
  float m[SPL_], w[SPL_];
  float M = -1e30f;
#pragma unroll
  for (int s = 0; s < SPL_; ++s) { m[s] = PM[(rec0 + s) * 64 + row]; M = fmaxf(M, m[s]); }
  float denom = 0.f;
#pragma unroll
  for (int s = 0; s < SPL_; ++s) {
    w[s] = exp2f(m[s] - M);
    denom += w[s] * PLs[(rec0 + s) * 64 + row];
  }
  float num[8] = {};
#pragma unroll
  for (int s = 0; s < SPL_; ++s) {
    const float* po = PO + ((size_t)(rec0 + s) * 64 + row) * 32 + dh0;
    f32x4 a = *(const f32x4*)po;
    f32x4 c = *(const f32x4*)(po + 4);
#pragma unroll
    for (int j = 0; j < 4; ++j) { num[j] += w[s] * a[j]; num[4 + j] += w[s] * c[j]; }
  }
  const int n = qt * 64 + row;
  if (n < N_) {
    const float inv = 1.f / denom;
    bf8_t v;
#pragma unroll
    for (int j = 0; j < 8; ++j) v[j] = (short)f2b(num[j] * inv);
    *(bf8_t*)(aout + ((size_t)b * NPAD + n) * C_ + h * 32 + dh0) = v;
  }
}

// ---------------- output projection + bias + residual ---------------------------
__global__ __launch_bounds__(256) void oproj_k(
    const unsigned short* __restrict__ aout, const float* __restrict__ Wo,
    const float* __restrict__ bo, const float* __restrict__ query,
    float* __restrict__ out)
{
  __shared__ __align__(16) unsigned short Al[64][72];
  __shared__ __align__(16) unsigned short Bl[64][72];
  const int b = blockIdx.z, n0 = blockIdx.y * 64, d0 = blockIdx.x * 64;
  const int tid = threadIdx.x, lane = tid & 63, wv = tid >> 6;
  const int wm = wv >> 1, wn = wv & 1;
  const int sr = tid >> 2, sc = (tid & 3) * 16;
  const int fr = lane & 15, fg = lane >> 4;
  f32x4 acc[2][2] = {};

  for (int kt = 0; kt < 4; ++kt) {
    const int k0 = kt * 64;
    {
      const unsigned short* src = aout + ((size_t)b * NPAD + n0 + sr) * C_ + k0 + sc;
      *(bf8_t*)&Al[sr][sc]     = *(const bf8_t*)src;
      *(bf8_t*)&Al[sr][sc + 8] = *(const bf8_t*)(src + 8);
    }
    stage_cvt16(&Bl[sr][sc], Wo + (size_t)(d0 + sr) * C_ + k0 + sc);
    __syncthreads();
#pragma unroll
    for (int kh = 0; kh < 2; ++kh) {
      const int ko = kh * 32 + 8 * fg;
      bf8_t af[2], bq[2];
#pragma unroll
      for (int m = 0; m < 2; ++m) {
        af[m] = *(const bf8_t*)&Al[wm * 32 + m * 16 + fr][ko];
        bq[m] = *(const bf8_t*)&Bl[wn * 32 + m * 16 + fr][ko];
      }
#pragma unroll
      for (int m = 0; m < 2; ++m)
#pragma unroll
        for (int n = 0; n < 2; ++n)
          acc[m][n] = __builtin_amdgcn_mfma_f32_16x16x32_bf16(af[m], bq[n], acc[m][n], 0, 0, 0);
    }
    __syncthreads();
  }
#pragma unroll
  for (int m = 0; m < 2; ++m)
#pragma unroll
    for (int nn = 0; nn < 2; ++nn) {
      const int d = d0 + wn * 32 + nn * 16 + fr;
      const float bb = bo[d];
#pragma unroll
      for (int r = 0; r < 4; ++r) {
        const int n = n0 + wm * 32 + m * 16 + fg * 4 + r;
        if (n < N_) {
          const size_t gi = ((size_t)b * N_ + n) * C_ + d;
          out[gi] = acc[m][nn][r] + bb + query[gi];
        }
      }
    }
}

extern "C" void kernel_launch(void* const* d_in, const int* in_sizes, int n_in,
                              void* d_out, int out_size, void* d_ws, size_t ws_size,
                              hipStream_t stream)
{
  const float* query = (const float*)d_in[0];
  const float* key   = (const float*)d_in[1];
  const float* value = (const float*)d_in[2];
  const float* qpos  = (const float*)d_in[3];
  const float* kpos  = (const float*)d_in[4];
  const float* qsine = (const float*)d_in[5];
  const float* Wqc = (const float*)d_in[6];  const float* bqc = (const float*)d_in[7];
  const float* Wqp = (const float*)d_in[8];  const float* bqp = (const float*)d_in[9];
  const float* Wqs = (const float*)d_in[10]; const float* bqs = (const float*)d_in[11];
  const float* Wkc = (const float*)d_in[12]; const float* bkc = (const float*)d_in[13];
  const float* Wkp = (const float*)d_in[14]; const float* bkp = (const float*)d_in[15];
  const float* Wv  = (const float*)d_in[16]; const float* bv  = (const float*)d_in[17];
  const float* Wo  = (const float*)d_in[18]; const float* bo  = (const float*)d_in[19];

  // workspace layout
  const size_t qcat_b = (size_t)B_ * H_ * NPAD * 64 * 2;             //  2.62 MB
  const size_t kc_b   = (size_t)B_ * H_ * L_ * 32 * 2;               // 16.78 MB
  const size_t kp_b   = kc_b;                                        // 16.78 MB
  const size_t vt_b   = kc_b;                                        // 16.78 MB
  const size_t aout_b = (size_t)B_ * NPAD * C_ * 2;                  //  1.31 MB
  const size_t nrec   = (size_t)B_ * H_ * QT_ * SPL_;                // 1280
  const size_t po_b   = nrec * 64 * 32 * 4;                          // 10.49 MB
  const size_t pm_b   = nrec * 64 * 4;
  const size_t pl_b   = nrec * 64 * 4;
  const size_t wsw_b  = (size_t)24 * 256 * 64 * 2;                   //  0.79 MB (Wq 12x32KB + Wk 24x16KB)
  if (ws_size < qcat_b + kc_b + kp_b + vt_b + aout_b + po_b + pm_b + pl_b + wsw_b) return;
  char* ws = (char*)d_ws;
  unsigned short* Qcat = (unsigned short*)(ws);
  unsigned short* Kc   = (unsigned short*)(ws + qcat_b);
  unsigned short* Kp   = (unsigned short*)(ws + qcat_b + kc_b);
  unsigned short* Vt   = (unsigned short*)(ws + qcat_b + kc_b + kp_b);
  unsigned short* aout = (unsigned short*)(ws + qcat_b + kc_b + kp_b + vt_b);
  float* PO  = (float*)(ws + qcat_b + kc_b + kp_b + vt_b + aout_b);
  float* PM  = (float*)(ws + qcat_b + kc_b + kp_b + vt_b + aout_b + po_b);
  float* PLs = (float*)(ws + qcat_b + kc_b + kp_b + vt_b + aout_b + po_b + pm_b);
  unsigned short* Wq = (unsigned short*)(ws + qcat_b + kc_b + kp_b + vt_b + aout_b + po_b + pm_b + pl_b);
  unsigned short* Wk = Wq + (size_t)12 * 16384;      // after 12 x 32 KB q-slots
  float* out = (float*)d_out;

  wcvt_all_k<<<dim3(8, 3),                256, 0, stream>>>(Wkp, Wkc, Wv, Wqp, Wqc, Wqs, Wk, Wq);
  qproj_k  <<<dim3(B_ * QT_),             256, 0, stream>>>(qpos, query, qsine, Wq, bqp, bqc, bqs, Qcat);
  kvproj_k <<<dim3(512, 3),               256, 0, stream>>>(kpos, key, value, Wk, bkp, bkc, bv, Kc, Kp, Vt);
  attn_k   <<<dim3(QT_ * SPL_ * B_ * H_), 256, 0, stream>>>(Qcat, Kc, Kp, Vt, PO, PM, PLs);
  combine_k<<<dim3(QT_, 8, 8),            256, 0, stream>>>(PO, PM, PLs, aout);
  oproj_k  <<<dim3(4, QT_, 8),            256, 0, stream>>>(aout, Wo, bo, query, out);
}